// Round 3
// baseline (7807.806 us; speedup 1.0000x reference)
//
#include <hip/hip_runtime.h>
#include <hip/hip_bf16.h>
#include <math.h>

// AttentiveFP forward, f32, workspace-adaptive (edge/node chunking).
// H=128, 3H=384.

#define HD 128
#define H3 384

__device__ __forceinline__ float lrelu_f(float x) { return x > 0.f ? x : 0.01f * x; }
__device__ __forceinline__ float sigmoid_f(float x) { return 1.f / (1.f + expf(-x)); }

__device__ __forceinline__ void atomicMaxF(float* addr, float val) {
    int iv = __float_as_int(val);
    if (iv >= 0) atomicMax((int*)addr, iv);
    else atomicMin((unsigned int*)addr, (unsigned int)iv);
}

// ---------------------------------------------------------------------------
// Generic tiled GEMM: C[M,N] = act( A1[M,K1]@B1 (+ A2[M,K2]@B2) + bias )
//  - optional row gather on A1 (idx1), A2 is always chunk-local dense
//  - optional scatter epilogue: C[sidx[m]*N + c] += rscale[m] * v (atomic)
//  - act: 0=none, 1=leaky_relu(0.01), 2=relu
// Tile 64x64, BK=16, 256 threads, 4x4 per thread.
// ---------------------------------------------------------------------------
__global__ __launch_bounds__(256) void gemm_kernel(
    const float* __restrict__ A1, const int* __restrict__ idx1, int K1,
    const float* __restrict__ B1,
    const float* __restrict__ A2, int K2, const float* __restrict__ B2,
    const float* __restrict__ bias,
    float* __restrict__ C, int M, int N, int act,
    const int* __restrict__ sidx, const float* __restrict__ rscale)
{
    __shared__ float As[16][68];
    __shared__ float Bs[16][68];
    const int t = threadIdx.x;
    const int m0 = blockIdx.x * 64;
    const int n0 = blockIdx.y * 64;
    const int tx = t & 15, ty = t >> 4;
    const int ar = t >> 2;          // 0..63  (A row within tile)
    const int ak = (t & 3) << 2;    // 0,4,8,12 (A col within K-tile)
    int am = m0 + ar; if (am >= M) am = M - 1;
    const int bk = t >> 4;          // 0..15 (B row within K-tile)
    const int bn = (t & 15) << 2;   // B col within tile
    float acc[4][4] = {{0.f}};
    const int KT = (K1 + K2) >> 4;
    for (int kt = 0; kt < KT; ++kt) {
        int k0 = kt << 4;
        const float* A; const int* idx; int K; int ka; const float* B;
        if (k0 < K1) { A = A1; idx = idx1; K = K1; ka = k0; B = B1; }
        else         { A = A2; idx = nullptr; K = K2; ka = k0 - K1; B = B2; }
        size_t arow = idx ? (size_t)idx[am] : (size_t)am;
        float4 av = *reinterpret_cast<const float4*>(A + arow * (size_t)K + (ka + ak));
        As[ak + 0][ar] = av.x; As[ak + 1][ar] = av.y;
        As[ak + 2][ar] = av.z; As[ak + 3][ar] = av.w;
        float4 bv = *reinterpret_cast<const float4*>(B + (size_t)(ka + bk) * N + (n0 + bn));
        *reinterpret_cast<float4*>(&Bs[bk][bn]) = bv;
        __syncthreads();
#pragma unroll
        for (int kk = 0; kk < 16; ++kk) {
            const float4 a = *reinterpret_cast<const float4*>(&As[kk][ty << 2]);
            const float4 b = *reinterpret_cast<const float4*>(&Bs[kk][tx << 2]);
            const float aa[4] = {a.x, a.y, a.z, a.w};
            const float bb[4] = {b.x, b.y, b.z, b.w};
#pragma unroll
            for (int i = 0; i < 4; ++i)
#pragma unroll
                for (int j = 0; j < 4; ++j)
                    acc[i][j] = fmaf(aa[i], bb[j], acc[i][j]);
        }
        __syncthreads();
    }
#pragma unroll
    for (int i = 0; i < 4; ++i) {
        int m = m0 + (ty << 2) + i;
        if (m >= M) continue;
#pragma unroll
        for (int j = 0; j < 4; ++j) {
            int c = n0 + (tx << 2) + j;
            float v = acc[i][j] + bias[c];
            if (act == 1) v = v > 0.f ? v : 0.01f * v;
            else if (act == 2) v = fmaxf(v, 0.f);
            if (sidx) atomicAdd(&C[(size_t)sidx[m] * N + c], rscale[m] * v);
            else C[(size_t)m * N + c] = v;
        }
    }
}

__global__ void init_maxsum_kernel(float* mx, float* sm, int n) {
    int i = blockIdx.x * blockDim.x + threadIdx.x;
    if (i < n) { mx[i] = -__builtin_inff(); sm[i] = 0.f; }
}

// score[i] = lrelu( A[i,:]·w[0:128] + B[seg[i],:]·w[128:256] + bal ); 1 wave/row
__global__ __launch_bounds__(256) void score_kernel(
    const float* __restrict__ A, const float* __restrict__ B,
    const int* __restrict__ seg, const float* __restrict__ w,
    const float* __restrict__ bal, float* __restrict__ out,
    float* __restrict__ maxbuf, int count)
{
    int i = (blockIdx.x * blockDim.x + threadIdx.x) >> 6;
    int lane = threadIdx.x & 63;
    if (i >= count) return;
    int s = seg[i];
    const float* ar = A + (size_t)i * HD;
    const float* br = B + (size_t)s * HD;
    float p = ar[lane] * w[lane] + ar[lane + 64] * w[lane + 64]
            + br[lane] * w[128 + lane] + br[lane + 64] * w[192 + lane];
#pragma unroll
    for (int off = 32; off > 0; off >>= 1) p += __shfl_down(p, off);
    if (lane == 0) {
        float v = lrelu_f(p + bal[0]);
        out[i] = v;
        atomicMaxF(&maxbuf[s], v);
    }
}

__global__ void expsum_kernel(float* __restrict__ sc, const float* __restrict__ mx,
                              float* __restrict__ sm, const int* __restrict__ seg, int count) {
    int i = blockIdx.x * blockDim.x + threadIdx.x;
    if (i >= count) return;
    int s = seg[i];
    float p = expf(sc[i] - mx[s]);
    sc[i] = p;
    atomicAdd(&sm[s], p);
}

__global__ void attdiv_kernel(float* __restrict__ sc, const float* __restrict__ sm,
                              const int* __restrict__ seg, int count) {
    int i = blockIdx.x * blockDim.x + threadIdx.x;
    if (i >= count) return;
    sc[i] = sc[i] / sm[seg[i]];
}

__global__ void gru_gate_kernel(const float* __restrict__ gi, const float* __restrict__ gh,
                                const float* __restrict__ h, float* __restrict__ out, int M) {
    size_t idx = (size_t)blockIdx.x * blockDim.x + threadIdx.x;
    if (idx >= (size_t)M * HD) return;
    size_t row = idx >> 7; int col = (int)(idx & 127);
    const float* gir = gi + row * H3;
    const float* ghr = gh + row * H3;
    float r = sigmoid_f(gir[col] + ghr[col]);
    float z = sigmoid_f(gir[col + 128] + ghr[col + 128]);
    float nn = tanhf(gir[col + 256] + r * ghr[col + 256]);
    float o = (1.f - z) * nn + z * h[idx];
    out[idx] = fmaxf(o, 0.f);
}

__global__ void elu_ip_kernel(float* __restrict__ x, size_t n) {
    size_t i = (size_t)blockIdx.x * blockDim.x + threadIdx.x;
    if (i >= n) return;
    float v = x[i];
    x[i] = v > 0.f ? v : expf(v) - 1.f;
}

__global__ void lrelu_copy_kernel(const float* __restrict__ in, float* __restrict__ out, size_t n) {
    size_t i = (size_t)blockIdx.x * blockDim.x + threadIdx.x;
    if (i >= n) return;
    out[i] = lrelu_f(in[i]);
}

__global__ void segsum_kernel(const float* __restrict__ nb, const int* __restrict__ gid,
                              float* __restrict__ sn, int Nn) {
    size_t idx = (size_t)blockIdx.x * blockDim.x + threadIdx.x;
    if (idx >= (size_t)Nn * HD) return;
    size_t row = idx >> 7; int col = (int)(idx & 127);
    atomicAdd(&sn[(size_t)gid[row] * HD + col], nb[idx]);
}

__global__ void final_kernel(const float* __restrict__ sn, const float* __restrict__ Wp,
                             const float* __restrict__ bp, float* __restrict__ out, int G) {
    int g = (blockIdx.x * blockDim.x + threadIdx.x) >> 6;
    int lane = threadIdx.x & 63;
    if (g >= G) return;
    const float* r = sn + (size_t)g * HD;
    float p = r[lane] * Wp[lane] + r[lane + 64] * Wp[lane + 64];
#pragma unroll
    for (int off = 32; off > 0; off >>= 1) p += __shfl_down(p, off);
    if (lane == 0) out[g] = p + bp[0];
}

// workspace-too-small canary: distinctive output so the failure mode is visible
__global__ void canary_kernel(float* out, int n) {
    int i = blockIdx.x * blockDim.x + threadIdx.x;
    if (i < n) out[i] = 123.456f;
}

extern "C" void kernel_launch(void* const* d_in, const int* in_sizes, int n_in,
                              void* d_out, int out_size, void* d_ws, size_t ws_size,
                              hipStream_t stream) {
    const float* node = (const float*)d_in[0];
    const float* edge = (const float*)d_in[1];
    const int*   src  = (const int*)d_in[2];
    const int*   dst  = (const int*)d_in[3];
    const int*   gid  = (const int*)d_in[4];
    const float* Wn0  = (const float*)d_in[5];
    const float* bn0  = (const float*)d_in[6];
    const float* We0  = (const float*)d_in[7];
    const float* be0  = (const float*)d_in[8];
    const float* aWn  = (const float*)d_in[9];
    const float* abn  = (const float*)d_in[10];
    const float* aWe  = (const float*)d_in[11];
    const float* abe  = (const float*)d_in[12];
    const float* aWal = (const float*)d_in[13];
    const float* abal = (const float*)d_in[14];
    const float* aWat = (const float*)d_in[15];
    const float* abat = (const float*)d_in[16];
    const float* aWih = (const float*)d_in[17];
    const float* abih = (const float*)d_in[18];
    const float* aWhh = (const float*)d_in[19];
    const float* abhh = (const float*)d_in[20];
    const float* mWal = (const float*)d_in[21];
    const float* mbal = (const float*)d_in[22];
    const float* mWat = (const float*)d_in[23];
    const float* mbat = (const float*)d_in[24];
    const float* mWih = (const float*)d_in[25];
    const float* mbih = (const float*)d_in[26];
    const float* mWhh = (const float*)d_in[27];
    const float* mbhh = (const float*)d_in[28];
    const float* Wp   = (const float*)d_in[29];
    const float* bp   = (const float*)d_in[30];

    const int N = in_sizes[0] / 64;
    const int E = in_sizes[1] / 16;
    const int G = out_size;
    const int D = in_sizes[9] / (HD * HD);
    const int L = in_sizes[21] / (2 * HD);

    // ---- fixed workspace layout ----
    char* wsb = (char*)d_ws;
    size_t off = 0;
    auto alloc = [&](size_t bytes) -> float* {
        float* p = (float*)(wsb + off);
        off += (bytes + 255) & ~(size_t)255;
        return p;
    };
    float* nbuf = alloc((size_t)N * HD * 4);   // node states n
    float* hbuf = alloc((size_t)N * HD * 4);   // h (transformed nodes)
    float* ctx  = alloc((size_t)N * HD * 4);   // attention context
    float* sc_e = alloc((size_t)E * 4);        // edge scores -> att weights
    float* nmax = alloc((size_t)N * 4);
    float* nsum = alloc((size_t)N * 4);
    float* sc_n = alloc((size_t)N * 4);
    float* sn   = alloc((size_t)G * HD * 4);
    float* sbuf = alloc((size_t)G * HD * 4);
    float* sctx = alloc((size_t)G * HD * 4);
    float* gim  = alloc((size_t)G * H3 * 4);
    float* ghm  = alloc((size_t)G * H3 * 4);
    float* gmax = alloc((size_t)G * 4);
    float* gsum = alloc((size_t)G * 4);
    // ---- pool (chunk buffers), sized by what's left ----
    size_t pool_bytes = (off <= ws_size) ? (ws_size - off) - ((ws_size - off) & 255) : 0;
    // edge chunk: CE rows of e (HD f32) + msg (HD f32)
    long long ce_ll = (long long)(pool_bytes / (2 * HD * 4)) - 64;
    // node chunk: CN rows of gi (H3 f32) + gh (H3 f32)
    long long cn_ll = (long long)(pool_bytes / (2 * H3 * 4)) - 64;
    int CE = (int)(ce_ll < 0 ? 0 : ce_ll); CE &= ~63; if (CE > E) CE = E;
    int CN = (int)(cn_ll < 0 ? 0 : cn_ll); CN &= ~63; if (CN > N) CN = N;
    if (CE < 1024 || CN < 1024) {  // can't run: canary output
        canary_kernel<<<(G + 255) / 256, 256, 0, stream>>>((float*)d_out, G);
        return;
    }
    float* echunk = (float*)(wsb + off);
    float* mchunk = echunk + (size_t)CE * HD;
    float* gi     = (float*)(wsb + off);          // overlays echunk (different phase)
    float* gh     = gi + (size_t)CN * H3;
    const int nec = (E + CE - 1) / CE;
    const int nnc = (N + CN - 1) / CN;
    const bool eFull = (CE >= E);

    auto gemm = [&](const float* A1, const int* i1, int K1, const float* B1,
                    const float* A2, int K2, const float* B2,
                    const float* bias, float* C, int M, int Nc, int act,
                    const int* sidx, const float* rsc) {
        dim3 g((M + 63) / 64, Nc / 64);
        gemm_kernel<<<g, dim3(256), 0, stream>>>(A1, i1, K1, B1, A2, K2, B2,
                                                 bias, C, M, Nc, act, sidx, rsc);
    };

    // ---- input embeddings ----
    gemm(node, nullptr, 64, Wn0, nullptr, 0, nullptr, bn0, nbuf, N, HD, 1, nullptr, nullptr);
    if (eFull)  // e fits entirely: compute once, reuse within depth
        gemm(edge, nullptr, 16, We0, nullptr, 0, nullptr, be0, echunk, E, HD, 1, nullptr, nullptr);

    // ---- atom-level message passing ----
    for (int d = 0; d < D; ++d) {
        const float* Wn_d  = aWn  + (size_t)d * HD * HD;
        const float* bn_d  = abn  + (size_t)d * HD;
        const float* We_d  = aWe  + (size_t)d * 2 * HD * HD;
        const float* be_d  = abe  + (size_t)d * HD;
        const float* Wal_d = aWal + (size_t)d * 2 * HD;
        const float* bal_d = abal + d;
        const float* Wat_d = aWat + (size_t)d * HD * HD;
        const float* bat_d = abat + (size_t)d * HD;
        const float* Wih_d = aWih + (size_t)d * HD * H3;
        const float* bih_d = abih + (size_t)d * H3;
        const float* Whh_d = aWhh + (size_t)d * HD * H3;
        const float* bhh_d = abhh + (size_t)d * H3;

        // h = lrelu(n @ Wn + bn)
        gemm(nbuf, nullptr, HD, Wn_d, nullptr, 0, nullptr, bn_d, hbuf, N, HD, 1, nullptr, nullptr);

        // pass A: msg chunks -> scores + segment max
        init_maxsum_kernel<<<(N + 255) / 256, 256, 0, stream>>>(nmax, nsum, N);
        for (int c = 0; c < nec; ++c) {
            int c0 = c * CE, ce = (E - c0 < CE) ? E - c0 : CE;
            if (!eFull)
                gemm(edge + (size_t)c0 * 16, nullptr, 16, We0, nullptr, 0, nullptr,
                     be0, echunk, ce, HD, 1, nullptr, nullptr);
            gemm(hbuf, src + c0, HD, We_d, echunk, HD, We_d + HD * HD,
                 be_d, mchunk, ce, HD, 1, nullptr, nullptr);
            score_kernel<<<(ce + 3) / 4, 256, 0, stream>>>(mchunk, hbuf, dst + c0,
                                                           Wal_d, bal_d, sc_e + c0, nmax, ce);
        }
        expsum_kernel<<<(E + 255) / 256, 256, 0, stream>>>(sc_e, nmax, nsum, dst, E);
        attdiv_kernel<<<(E + 255) / 256, 256, 0, stream>>>(sc_e, nsum, dst, E);

        // pass B: recompute msg chunks -> weighted projection scatter into ctx
        hipMemsetAsync(ctx, 0, (size_t)N * HD * 4, stream);
        for (int c = 0; c < nec; ++c) {
            int c0 = c * CE, ce = (E - c0 < CE) ? E - c0 : CE;
            if (nec > 1) {  // single-chunk case: mchunk still holds pass-A msg
                gemm(edge + (size_t)c0 * 16, nullptr, 16, We0, nullptr, 0, nullptr,
                     be0, echunk, ce, HD, 1, nullptr, nullptr);
                gemm(hbuf, src + c0, HD, We_d, echunk, HD, We_d + HD * HD,
                     be_d, mchunk, ce, HD, 1, nullptr, nullptr);
            }
            gemm(mchunk, nullptr, HD, Wat_d, nullptr, 0, nullptr, bat_d,
                 ctx, ce, HD, 0, dst + c0, sc_e + c0);
        }
        elu_ip_kernel<<<((size_t)N * HD + 255) / 256, 256, 0, stream>>>(ctx, (size_t)N * HD);

        // GRU (node-chunked): gi = ctx@Wih+bih ; gh = h@Whh+bhh ; n = relu(gru)
        for (int c = 0; c < nnc; ++c) {
            int c0 = c * CN, cn = (N - c0 < CN) ? N - c0 : CN;
            gemm(ctx + (size_t)c0 * HD, nullptr, HD, Wih_d, nullptr, 0, nullptr,
                 bih_d, gi, cn, H3, 0, nullptr, nullptr);
            gemm(hbuf + (size_t)c0 * HD, nullptr, HD, Whh_d, nullptr, 0, nullptr,
                 bhh_d, gh, cn, H3, 0, nullptr, nullptr);
            gru_gate_kernel<<<((size_t)cn * HD + 255) / 256, 256, 0, stream>>>(
                gi, gh, hbuf + (size_t)c0 * HD, nbuf + (size_t)c0 * HD, cn);
        }
        if (eFull && d + 1 < D)
            gemm(edge, nullptr, 16, We0, nullptr, 0, nullptr, be0, echunk, E, HD, 1,
                 nullptr, nullptr);  // recompute e (GRU gi/gh overlaid the pool)
    }

    // ---- molecule-level readout ----
    hipMemsetAsync(sn, 0, (size_t)G * HD * 4, stream);
    segsum_kernel<<<((size_t)N * HD + 255) / 256, 256, 0, stream>>>(nbuf, gid, sn, N);
    for (int l = 0; l < L; ++l) {
        const float* Wal_l = mWal + (size_t)l * 2 * HD;
        const float* bal_l = mbal + l;
        const float* Wat_l = mWat + (size_t)l * HD * HD;
        const float* bat_l = mbat + (size_t)l * HD;
        const float* Wih_l = mWih + (size_t)l * HD * H3;
        const float* bih_l = mbih + (size_t)l * H3;
        const float* Whh_l = mWhh + (size_t)l * HD * H3;
        const float* bhh_l = mbhh + (size_t)l * H3;

        lrelu_copy_kernel<<<((size_t)G * HD + 255) / 256, 256, 0, stream>>>(sn, sbuf, (size_t)G * HD);
        init_maxsum_kernel<<<(G + 255) / 256, 256, 0, stream>>>(gmax, gsum, G);
        score_kernel<<<(N + 3) / 4, 256, 0, stream>>>(nbuf, sbuf, gid, Wal_l, bal_l, sc_n, gmax, N);
        expsum_kernel<<<(N + 255) / 256, 256, 0, stream>>>(sc_n, gmax, gsum, gid, N);
        attdiv_kernel<<<(N + 255) / 256, 256, 0, stream>>>(sc_n, gsum, gid, N);
        hipMemsetAsync(sctx, 0, (size_t)G * HD * 4, stream);
        gemm(nbuf, nullptr, HD, Wat_l, nullptr, 0, nullptr, bat_l, sctx, N, HD, 0, gid, sc_n);
        elu_ip_kernel<<<((size_t)G * HD + 255) / 256, 256, 0, stream>>>(sctx, (size_t)G * HD);
        gemm(sctx, nullptr, HD, Wih_l, nullptr, 0, nullptr, bih_l, gim, G, H3, 0, nullptr, nullptr);
        gemm(sbuf, nullptr, HD, Whh_l, nullptr, 0, nullptr, bhh_l, ghm, G, H3, 0, nullptr, nullptr);
        gru_gate_kernel<<<((size_t)G * HD + 255) / 256, 256, 0, stream>>>(gim, ghm, sbuf, sn, G);
    }

    // ---- final prediction ----
    final_kernel<<<(G + 3) / 4, 256, 0, stream>>>(sn, Wp, bp, (float*)d_out, G);
}

// Round 6
// 5049.455 us; speedup vs baseline: 1.5463x; 1.5463x over previous
//
#include <hip/hip_runtime.h>
#include <hip/hip_bf16.h>
#include <math.h>

// AttentiveFP forward. Split-bf16 (3-term) MFMA GEMM engine, fused score
// row-dots, workspace-adaptive chunking. H=128, 3H=384.

#define HD 128
#define H3 384

typedef __attribute__((ext_vector_type(8))) short short8;
typedef __attribute__((ext_vector_type(4))) float f32x4;

__device__ __forceinline__ float lrelu_f(float x) { return x > 0.f ? x : 0.01f * x; }
__device__ __forceinline__ float sigmoid_f(float x) { return 1.f / (1.f + expf(-x)); }

__device__ __forceinline__ void atomicMaxF(float* addr, float val) {
    int iv = __float_as_int(val);
    if (iv >= 0) atomicMax((int*)addr, iv);
    else atomicMin((unsigned int*)addr, (unsigned int)iv);
}

// round-to-nearest-even f32 -> bf16 (bit trick); returns bits, *back = value as f32
__device__ __forceinline__ unsigned short bf16_rne(float v, float* back) {
    unsigned u = __float_as_uint(v);
    unsigned r = (u + 0x7FFFu + ((u >> 16) & 1u)) >> 16;
    *back = __uint_as_float(r << 16);
    return (unsigned short)r;
}

// ---------------------------------------------------------------------------
// Pack B [K,N] f32 into MFMA-fragment-ordered bf16 hi/lo:
// layout [nblk=N/16][kg=0..KG-1][col 0..15][e 0..7], KG = 4*ceil(K/32).
// Lane l of a wave reading tile (kst,nblk) fetches 16B at
// ((nblk*KG + kst*4 + (l>>4))*16 + (l&15))*16 bytes -> wave reads 1KB contig.
// ---------------------------------------------------------------------------
__global__ void pack_b_kernel(const float* __restrict__ B, int K, int N,
                              short* __restrict__ hi, short* __restrict__ lo) {
    int KG = 4 * ((K + 31) / 32);
    int idx = blockIdx.x * blockDim.x + threadIdx.x;
    int total = (N >> 4) * KG * 16;
    if (idx >= total) return;
    int col = idx & 15;
    int kg = (idx >> 4) % KG;
    int nblk = idx / (16 * KG);
    size_t o = (size_t)idx * 8;
#pragma unroll
    for (int e = 0; e < 8; ++e) {
        int k = kg * 8 + e;
        float v = (k < K) ? B[(size_t)k * N + nblk * 16 + col] : 0.f;
        float hf;
        unsigned short h = bf16_rne(v, &hf);
        float dummy;
        unsigned short l = bf16_rne(v - hf, &dummy);
        hi[o + e] = (short)h;
        lo[o + e] = (short)l;
    }
}

// ---------------------------------------------------------------------------
// Split-bf16 MFMA GEMM: C[M,N] = act( A[M,K1+K2] @ B + bias )
//  A = [A1 (opt row-gather idx1) | A2]; B pre-packed hi/lo (frag order)
//  3-term compensation: hi*hi + hi*lo + lo*hi  (~f32 accuracy)
//  optional scatter epilogue: C[sidx[m]*N+c] += rscale[m]*v (atomic)
//  optional rowdot epilogue: rdout[m] += sum_c rdw[c]*v (atomic, post-act)
// Tile 64x64, 4 waves (wave -> 32x32 quadrant of 2x2 MFMA 16x16x32 tiles).
// No LDS: A frags direct to regs (split in-register), B frags from L2.
// ---------------------------------------------------------------------------
__global__ __launch_bounds__(256) void mfma_gemm(
    const float* __restrict__ A1, const int* __restrict__ idx1, int K1,
    const float* __restrict__ A2, int K2,
    const short* __restrict__ Bhi, const short* __restrict__ Blo, int KG,
    const float* __restrict__ bias,
    float* __restrict__ C, int M, int N, int act,
    const int* __restrict__ sidx, const float* __restrict__ rscale,
    const float* __restrict__ rdw, float* __restrict__ rdout)
{
    const int t = threadIdx.x;
    const int lane = t & 63;
    const int w = t >> 6;
    const int wm = w & 1, wn = w >> 1;
    const int m0 = blockIdx.x * 64;
    const int n0 = blockIdx.y * 64;
    const int q = lane >> 4;
    const int r16 = lane & 15;
    const int K = K1 + K2;
    const int KT = (K + 31) >> 5;

    f32x4 acc[2][2];
#pragma unroll
    for (int mt = 0; mt < 2; ++mt)
#pragma unroll
        for (int nt = 0; nt < 2; ++nt) {
            acc[mt][nt][0] = 0.f; acc[mt][nt][1] = 0.f;
            acc[mt][nt][2] = 0.f; acc[mt][nt][3] = 0.f;
        }

    int mrowc[2], grow[2];
#pragma unroll
    for (int mt = 0; mt < 2; ++mt) {
        int m = m0 + (wm << 5) + (mt << 4) + r16;
        if (m >= M) m = M - 1;
        mrowc[mt] = m;
        grow[mt] = idx1 ? idx1[m] : m;
    }

    for (int kt = 0; kt < KT; ++kt) {
        const int c8 = (kt << 5) + (q << 3);  // this lane's 8-k chunk
        short8 ah[2], al[2], bh[2], bl[2];
#pragma unroll
        for (int mt = 0; mt < 2; ++mt) {
            const float* p = nullptr;
            if (c8 < K1) p = A1 + (size_t)grow[mt] * K1 + c8;
            else if (c8 < K) p = A2 + (size_t)mrowc[mt] * K2 + (c8 - K1);
            if (p) {
                float4 u0 = *reinterpret_cast<const float4*>(p);
                float4 u1 = *reinterpret_cast<const float4*>(p + 4);
                float vv[8] = {u0.x, u0.y, u0.z, u0.w, u1.x, u1.y, u1.z, u1.w};
#pragma unroll
                for (int j = 0; j < 8; ++j) {
                    float back, dummy;
                    ah[mt][j] = (short)bf16_rne(vv[j], &back);
                    al[mt][j] = (short)bf16_rne(vv[j] - back, &dummy);
                }
            } else {
#pragma unroll
                for (int j = 0; j < 8; ++j) { ah[mt][j] = 0; al[mt][j] = 0; }
            }
        }
        const int kg = (kt << 2) + q;
#pragma unroll
        for (int nt = 0; nt < 2; ++nt) {
            int nblk = (n0 >> 4) + (wn << 1) + nt;
            size_t boff = (((size_t)nblk * KG + kg) * 16 + r16) * 8;
            bh[nt] = *reinterpret_cast<const short8*>(Bhi + boff);
            bl[nt] = *reinterpret_cast<const short8*>(Blo + boff);
        }
#pragma unroll
        for (int mt = 0; mt < 2; ++mt)
#pragma unroll
            for (int nt = 0; nt < 2; ++nt) {
                acc[mt][nt] = __builtin_amdgcn_mfma_f32_16x16x32_bf16(ah[mt], bh[nt], acc[mt][nt], 0, 0, 0);
                acc[mt][nt] = __builtin_amdgcn_mfma_f32_16x16x32_bf16(ah[mt], bl[nt], acc[mt][nt], 0, 0, 0);
                acc[mt][nt] = __builtin_amdgcn_mfma_f32_16x16x32_bf16(al[mt], bh[nt], acc[mt][nt], 0, 0, 0);
            }
    }

    // epilogue: C/D frag layout col = lane&15, row = (lane>>4)*4 + i
#pragma unroll
    for (int mt = 0; mt < 2; ++mt) {
        float pv[4] = {0.f, 0.f, 0.f, 0.f};
#pragma unroll
        for (int nt = 0; nt < 2; ++nt) {
            int col = n0 + (wn << 5) + (nt << 4) + r16;
            float bi = bias ? bias[col] : 0.f;
            float wc = rdw ? rdw[col] : 0.f;
#pragma unroll
            for (int i = 0; i < 4; ++i) {
                int m = m0 + (wm << 5) + (mt << 4) + (q << 2) + i;
                float v = acc[mt][nt][i] + bi;
                if (act == 1) v = v > 0.f ? v : 0.01f * v;
                else if (act == 2) v = fmaxf(v, 0.f);
                pv[i] += wc * v;
                if (m < M) {
                    if (sidx) atomicAdd(&C[(size_t)sidx[m] * N + col], rscale[m] * v);
                    else C[(size_t)m * N + col] = v;
                }
            }
        }
        if (rdw) {
#pragma unroll
            for (int i = 0; i < 4; ++i) {
                float p = pv[i];
                p += __shfl_xor(p, 1); p += __shfl_xor(p, 2);
                p += __shfl_xor(p, 4); p += __shfl_xor(p, 8);
                int m = m0 + (wm << 5) + (mt << 4) + (q << 2) + i;
                if (r16 == 0 && m < M) atomicAdd(&rdout[m], p);
            }
        }
    }
}

__global__ void init_maxsum_kernel(float* mx, float* sm, int n) {
    int i = blockIdx.x * blockDim.x + threadIdx.x;
    if (i < n) { mx[i] = -__builtin_inff(); sm[i] = 0.f; }
}

// sc[i] = lrelu(sc[i] + hd2[dst[i]] + bal); atomicMax into maxbuf[dst]
__global__ void score_combine_kernel(float* __restrict__ sc, const float* __restrict__ hd2,
                                     const int* __restrict__ seg, const float* __restrict__ bal,
                                     float* __restrict__ maxbuf, int count) {
    int i = blockIdx.x * blockDim.x + threadIdx.x;
    if (i >= count) return;
    int s = seg[i];
    float v = lrelu_f(sc[i] + hd2[s] + bal[0]);
    sc[i] = v;
    atomicMaxF(&maxbuf[s], v);
}

// mol-phase score: 1 wave/row, w is [256]
__global__ __launch_bounds__(256) void score_kernel(
    const float* __restrict__ A, const float* __restrict__ B,
    const int* __restrict__ seg, const float* __restrict__ w,
    const float* __restrict__ bal, float* __restrict__ out,
    float* __restrict__ maxbuf, int count)
{
    int i = (blockIdx.x * blockDim.x + threadIdx.x) >> 6;
    int lane = threadIdx.x & 63;
    if (i >= count) return;
    int s = seg[i];
    const float* ar = A + (size_t)i * HD;
    const float* br = B + (size_t)s * HD;
    float p = ar[lane] * w[lane] + ar[lane + 64] * w[lane + 64]
            + br[lane] * w[128 + lane] + br[lane + 64] * w[192 + lane];
#pragma unroll
    for (int off = 32; off > 0; off >>= 1) p += __shfl_down(p, off);
    if (lane == 0) {
        float v = lrelu_f(p + bal[0]);
        out[i] = v;
        atomicMaxF(&maxbuf[s], v);
    }
}

__global__ void expsum_kernel(float* __restrict__ sc, const float* __restrict__ mx,
                              float* __restrict__ sm, const int* __restrict__ seg, int count) {
    int i = blockIdx.x * blockDim.x + threadIdx.x;
    if (i >= count) return;
    int s = seg[i];
    float p = expf(sc[i] - mx[s]);
    sc[i] = p;
    atomicAdd(&sm[s], p);
}

__global__ void attdiv_kernel(float* __restrict__ sc, const float* __restrict__ sm,
                              const int* __restrict__ seg, int count) {
    int i = blockIdx.x * blockDim.x + threadIdx.x;
    if (i >= count) return;
    sc[i] = sc[i] / sm[seg[i]];
}

__global__ void gru_gate_kernel(const float* __restrict__ gi, const float* __restrict__ gh,
                                const float* __restrict__ h, float* __restrict__ out, int M) {
    size_t idx = (size_t)blockIdx.x * blockDim.x + threadIdx.x;
    if (idx >= (size_t)M * HD) return;
    size_t row = idx >> 7; int col = (int)(idx & 127);
    const float* gir = gi + row * H3;
    const float* ghr = gh + row * H3;
    float r = sigmoid_f(gir[col] + ghr[col]);
    float z = sigmoid_f(gir[col + 128] + ghr[col + 128]);
    float nn = tanhf(gir[col + 256] + r * ghr[col + 256]);
    float o = (1.f - z) * nn + z * h[idx];
    out[idx] = fmaxf(o, 0.f);
}

__global__ void elu_ip_kernel(float* __restrict__ x, size_t n) {
    size_t i = (size_t)blockIdx.x * blockDim.x + threadIdx.x;
    if (i >= n) return;
    float v = x[i];
    x[i] = v > 0.f ? v : expf(v) - 1.f;
}

__global__ void lrelu_copy_kernel(const float* __restrict__ in, float* __restrict__ out, size_t n) {
    size_t i = (size_t)blockIdx.x * blockDim.x + threadIdx.x;
    if (i >= n) return;
    out[i] = lrelu_f(in[i]);
}

__global__ void segsum_kernel(const float* __restrict__ nb, const int* __restrict__ gid,
                              float* __restrict__ sn, int Nn) {
    size_t idx = (size_t)blockIdx.x * blockDim.x + threadIdx.x;
    if (idx >= (size_t)Nn * HD) return;
    size_t row = idx >> 7; int col = (int)(idx & 127);
    atomicAdd(&sn[(size_t)gid[row] * HD + col], nb[idx]);
}

__global__ void final_kernel(const float* __restrict__ sn, const float* __restrict__ Wp,
                             const float* __restrict__ bp, float* __restrict__ out, int G) {
    int g = (blockIdx.x * blockDim.x + threadIdx.x) >> 6;
    int lane = threadIdx.x & 63;
    if (g >= G) return;
    const float* r = sn + (size_t)g * HD;
    float p = r[lane] * Wp[lane] + r[lane + 64] * Wp[lane + 64];
#pragma unroll
    for (int off = 32; off > 0; off >>= 1) p += __shfl_down(p, off);
    if (lane == 0) out[g] = p + bp[0];
}

__global__ void canary_kernel(float* out, int n) {
    int i = blockIdx.x * blockDim.x + threadIdx.x;
    if (i < n) out[i] = 123.456f;
}

struct PkB { const short* hi; const short* lo; int KG; };

extern "C" void kernel_launch(void* const* d_in, const int* in_sizes, int n_in,
                              void* d_out, int out_size, void* d_ws, size_t ws_size,
                              hipStream_t stream) {
    const float* node = (const float*)d_in[0];
    const float* edge = (const float*)d_in[1];
    const int*   src  = (const int*)d_in[2];
    const int*   dst  = (const int*)d_in[3];
    const int*   gid  = (const int*)d_in[4];
    const float* Wn0  = (const float*)d_in[5];
    const float* bn0  = (const float*)d_in[6];
    const float* We0  = (const float*)d_in[7];
    const float* be0  = (const float*)d_in[8];
    const float* aWn  = (const float*)d_in[9];
    const float* abn  = (const float*)d_in[10];
    const float* aWe  = (const float*)d_in[11];
    const float* abe  = (const float*)d_in[12];
    const float* aWal = (const float*)d_in[13];
    const float* abal = (const float*)d_in[14];
    const float* aWat = (const float*)d_in[15];
    const float* abat = (const float*)d_in[16];
    const float* aWih = (const float*)d_in[17];
    const float* abih = (const float*)d_in[18];
    const float* aWhh = (const float*)d_in[19];
    const float* abhh = (const float*)d_in[20];
    const float* mWal = (const float*)d_in[21];
    const float* mbal = (const float*)d_in[22];
    const float* mWat = (const float*)d_in[23];
    const float* mbat = (const float*)d_in[24];
    const float* mWih = (const float*)d_in[25];
    const float* mbih = (const float*)d_in[26];
    const float* mWhh = (const float*)d_in[27];
    const float* mbhh = (const float*)d_in[28];
    const float* Wp   = (const float*)d_in[29];
    const float* bp   = (const float*)d_in[30];

    const int N = in_sizes[0] / 64;
    const int E = in_sizes[1] / 16;
    const int G = out_size;
    const int D = in_sizes[9] / (HD * HD);
    const int L = in_sizes[21] / (2 * HD);
    if (D > 8 || L > 4) return;

    char* wsb = (char*)d_ws;

    // ---- weight pre-pack region (start of ws) ----
    short* pkcur = (short*)wsb;
    auto packB = [&](const float* B, int K, int Nc) -> PkB {
        int KG = 4 * ((K + 31) / 32);
        size_t elems = (size_t)(Nc >> 4) * KG * 16 * 8;
        short* hi = pkcur; pkcur += elems;
        short* lo = pkcur; pkcur += elems;
        int total = (Nc >> 4) * KG * 16;
        pack_b_kernel<<<(total + 255) / 256, 256, 0, stream>>>(B, K, Nc, hi, lo);
        PkB p; p.hi = hi; p.lo = lo; p.KG = KG; return p;
    };
    PkB pWn0 = packB(Wn0, 64, HD);
    PkB pWe0 = packB(We0, 16, HD);
    PkB pAWn[8], pAWe[8], pAWat[8], pAWih[8], pAWhh[8];
    for (int d = 0; d < D; ++d) {
        pAWn[d]  = packB(aWn  + (size_t)d * HD * HD,     HD,     HD);
        pAWe[d]  = packB(aWe  + (size_t)d * 2 * HD * HD, 2 * HD, HD);
        pAWat[d] = packB(aWat + (size_t)d * HD * HD,     HD,     HD);
        pAWih[d] = packB(aWih + (size_t)d * HD * H3,     HD,     H3);
        pAWhh[d] = packB(aWhh + (size_t)d * HD * H3,     HD,     H3);
    }
    PkB pMWat[4], pMWih[4], pMWhh[4];
    for (int l = 0; l < L; ++l) {
        pMWat[l] = packB(mWat + (size_t)l * HD * HD, HD, HD);
        pMWih[l] = packB(mWih + (size_t)l * HD * H3, HD, H3);
        pMWhh[l] = packB(mWhh + (size_t)l * HD * H3, HD, H3);
    }

    // ---- fixed f32 workspace ----
    size_t off = ((size_t)((char*)pkcur - wsb) + 255) & ~(size_t)255;
    auto alloc = [&](size_t bytes) -> float* {
        float* p = (float*)(wsb + off);
        off += (bytes + 255) & ~(size_t)255;
        return p;
    };
    float* nbuf = alloc((size_t)N * HD * 4);
    float* hbuf = alloc((size_t)N * HD * 4);
    float* ctx  = alloc((size_t)N * HD * 4);
    float* sc_e = alloc((size_t)E * 4);
    float* nmax = alloc((size_t)N * 4);
    float* nsum = alloc((size_t)N * 4);
    float* sc_n = alloc((size_t)N * 4);
    float* hd2  = alloc((size_t)N * 4);
    float* sn   = alloc((size_t)G * HD * 4);
    float* sbuf = alloc((size_t)G * HD * 4);
    float* sctx = alloc((size_t)G * HD * 4);
    float* gim  = alloc((size_t)G * H3 * 4);
    float* ghm  = alloc((size_t)G * H3 * 4);
    float* gmax = alloc((size_t)G * 4);
    float* gsum = alloc((size_t)G * 4);
    // ---- adaptive pool ----
    size_t pool_bytes = (off <= ws_size) ? (ws_size - off) - ((ws_size - off) & 255) : 0;
    long long ce_ll = (long long)(pool_bytes / (2 * HD * 4)) - 64;
    long long cn_ll = (long long)(pool_bytes / (2 * H3 * 4)) - 64;
    int CE = (int)(ce_ll < 0 ? 0 : ce_ll); CE &= ~63; if (CE > E) CE = E;
    int CN = (int)(cn_ll < 0 ? 0 : cn_ll); CN &= ~63; if (CN > N) CN = N;
    if (CE < 1024 || CN < 1024) {
        canary_kernel<<<(G + 255) / 256, 256, 0, stream>>>((float*)d_out, G);
        return;
    }
    float* echunk = (float*)(wsb + off);
    float* mchunk = echunk + (size_t)CE * HD;
    float* gi     = (float*)(wsb + off);
    float* gh     = gi + (size_t)CN * H3;
    const int nec = (E + CE - 1) / CE;
    const int nnc = (N + CN - 1) / CN;
    const bool eFull = (CE >= E);

    auto mgemm = [&](const float* A1, const int* i1, int K1, const float* A2, int K2,
                     const PkB& pk, const float* bias, float* C, int M, int Nc, int act,
                     const int* sidx, const float* rsc, const float* rdw, float* rdout) {
        dim3 g((M + 63) / 64, Nc / 64);
        mfma_gemm<<<g, dim3(256), 0, stream>>>(A1, i1, K1, A2, K2, pk.hi, pk.lo, pk.KG,
                                               bias, C, M, Nc, act, sidx, rsc, rdw, rdout);
    };

    // ---- input embeddings ----
    mgemm(node, nullptr, 64, nullptr, 0, pWn0, bn0, nbuf, N, HD, 1, nullptr, nullptr, nullptr, nullptr);
    if (eFull)
        mgemm(edge, nullptr, 16, nullptr, 0, pWe0, be0, echunk, E, HD, 1, nullptr, nullptr, nullptr, nullptr);

    // ---- atom-level message passing ----
    for (int d = 0; d < D; ++d) {
        const float* bn_d  = abn  + (size_t)d * HD;
        const float* be_d  = abe  + (size_t)d * HD;
        const float* Wal_d = aWal + (size_t)d * 2 * HD;
        const float* bal_d = abal + d;
        const float* bat_d = abat + (size_t)d * HD;
        const float* bih_d = abih + (size_t)d * H3;
        const float* bhh_d = abhh + (size_t)d * H3;

        hipMemsetAsync(hd2, 0, (size_t)N * 4, stream);
        hipMemsetAsync(sc_e, 0, (size_t)E * 4, stream);
        // h = lrelu(n @ Wn + bn); rowdot: hd2[n] += h . Wal[128:256]
        mgemm(nbuf, nullptr, HD, nullptr, 0, pAWn[d], bn_d, hbuf, N, HD, 1,
              nullptr, nullptr, Wal_d + HD, hd2);

        init_maxsum_kernel<<<(N + 255) / 256, 256, 0, stream>>>(nmax, nsum, N);
        // pass A: msg = lrelu([h[src],e]@We+be); rowdot: sc_e[e] += msg . Wal[0:128]
        for (int c = 0; c < nec; ++c) {
            int c0 = c * CE, ce = (E - c0 < CE) ? E - c0 : CE;
            if (!eFull)
                mgemm(edge + (size_t)c0 * 16, nullptr, 16, nullptr, 0, pWe0, be0,
                      echunk, ce, HD, 1, nullptr, nullptr, nullptr, nullptr);
            mgemm(hbuf, src + c0, HD, echunk, HD, pAWe[d], be_d, mchunk, ce, HD, 1,
                  nullptr, nullptr, Wal_d, sc_e + c0);
        }
        score_combine_kernel<<<(E + 255) / 256, 256, 0, stream>>>(sc_e, hd2, dst, bal_d, nmax, E);
        expsum_kernel<<<(E + 255) / 256, 256, 0, stream>>>(sc_e, nmax, nsum, dst, E);
        attdiv_kernel<<<(E + 255) / 256, 256, 0, stream>>>(sc_e, nsum, dst, E);

        // pass B: ctx = segsum(att * (msg @ Wat + bat), dst)
        hipMemsetAsync(ctx, 0, (size_t)N * HD * 4, stream);
        for (int c = 0; c < nec; ++c) {
            int c0 = c * CE, ce = (E - c0 < CE) ? E - c0 : CE;
            if (nec > 1) {  // recompute msg chunk (single-chunk: mchunk intact)
                mgemm(edge + (size_t)c0 * 16, nullptr, 16, nullptr, 0, pWe0, be0,
                      echunk, ce, HD, 1, nullptr, nullptr, nullptr, nullptr);
                mgemm(hbuf, src + c0, HD, echunk, HD, pAWe[d], be_d, mchunk, ce, HD, 1,
                      nullptr, nullptr, nullptr, nullptr);
            }
            mgemm(mchunk, nullptr, HD, nullptr, 0, pAWat[d], bat_d, ctx, ce, HD, 0,
                  dst + c0, sc_e + c0, nullptr, nullptr);
        }
        elu_ip_kernel<<<((size_t)N * HD + 255) / 256, 256, 0, stream>>>(ctx, (size_t)N * HD);

        // GRU (node-chunked)
        for (int c = 0; c < nnc; ++c) {
            int c0 = c * CN, cn = (N - c0 < CN) ? N - c0 : CN;
            mgemm(ctx + (size_t)c0 * HD, nullptr, HD, nullptr, 0, pAWih[d], bih_d,
                  gi, cn, H3, 0, nullptr, nullptr, nullptr, nullptr);
            mgemm(hbuf + (size_t)c0 * HD, nullptr, HD, nullptr, 0, pAWhh[d], bhh_d,
                  gh, cn, H3, 0, nullptr, nullptr, nullptr, nullptr);
            gru_gate_kernel<<<((size_t)cn * HD + 255) / 256, 256, 0, stream>>>(
                gi, gh, hbuf + (size_t)c0 * HD, nbuf + (size_t)c0 * HD, cn);
        }
        if (eFull && d + 1 < D)  // GRU gi/gh overlaid the pool: recompute e
            mgemm(edge, nullptr, 16, nullptr, 0, pWe0, be0, echunk, E, HD, 1,
                  nullptr, nullptr, nullptr, nullptr);
    }

    // ---- molecule-level readout ----
    hipMemsetAsync(sn, 0, (size_t)G * HD * 4, stream);
    segsum_kernel<<<((size_t)N * HD + 255) / 256, 256, 0, stream>>>(nbuf, gid, sn, N);
    for (int l = 0; l < L; ++l) {
        const float* Wal_l = mWal + (size_t)l * 2 * HD;
        const float* bal_l = mbal + l;
        const float* bat_l = mbat + (size_t)l * HD;
        const float* bih_l = mbih + (size_t)l * H3;
        const float* bhh_l = mbhh + (size_t)l * H3;

        lrelu_copy_kernel<<<((size_t)G * HD + 255) / 256, 256, 0, stream>>>(sn, sbuf, (size_t)G * HD);
        init_maxsum_kernel<<<(G + 255) / 256, 256, 0, stream>>>(gmax, gsum, G);
        score_kernel<<<(N + 3) / 4, 256, 0, stream>>>(nbuf, sbuf, gid, Wal_l, bal_l, sc_n, gmax, N);
        expsum_kernel<<<(N + 255) / 256, 256, 0, stream>>>(sc_n, gmax, gsum, gid, N);
        attdiv_kernel<<<(N + 255) / 256, 256, 0, stream>>>(sc_n, gsum, gid, N);
        hipMemsetAsync(sctx, 0, (size_t)G * HD * 4, stream);
        mgemm(nbuf, nullptr, HD, nullptr, 0, pMWat[l], bat_l, sctx, N, HD, 0,
              gid, sc_n, nullptr, nullptr);
        elu_ip_kernel<<<((size_t)G * HD + 255) / 256, 256, 0, stream>>>(sctx, (size_t)G * HD);
        mgemm(sctx, nullptr, HD, nullptr, 0, pMWih[l], bih_l, gim, G, H3, 0,
              nullptr, nullptr, nullptr, nullptr);
        mgemm(sbuf, nullptr, HD, nullptr, 0, pMWhh[l], bhh_l, ghm, G, H3, 0,
              nullptr, nullptr, nullptr, nullptr);
        gru_gate_kernel<<<((size_t)G * HD + 255) / 256, 256, 0, stream>>>(gim, ghm, sbuf, sn, G);
    }

    // ---- final prediction ----
    final_kernel<<<(G + 3) / 4, 256, 0, stream>>>(sn, Wp, bp, (float*)d_out, G);
}

// Round 8
// 2529.348 us; speedup vs baseline: 3.0869x; 1.9963x over previous
//
#include <hip/hip_runtime.h>
#include <hip/hip_bf16.h>
#include <math.h>

// AttentiveFP forward. Split-bf16 (3-term) MFMA engine with:
//  - fused e-on-the-fly edge kernel (LDS), rowdot pass A / att-scatter pass B
//  - sum(att)=1 algebraic move of Wat to node level (+ empty-segment rowmask)
//  - fused GRU (gate-sliced packed weights, no gi/gh materialization)
// H=128, 3H=384.

#define HD 128
#define H3 384

typedef __attribute__((ext_vector_type(8))) short short8;
typedef __attribute__((ext_vector_type(4))) float f32x4;

__device__ __forceinline__ float lrelu_f(float x) { return x > 0.f ? x : 0.01f * x; }
__device__ __forceinline__ float sigmoid_f(float x) { return 1.f / (1.f + expf(-x)); }

__device__ __forceinline__ void atomicMaxF(float* addr, float val) {
    int iv = __float_as_int(val);
    if (iv >= 0) atomicMax((int*)addr, iv);
    else atomicMin((unsigned int*)addr, (unsigned int)iv);
}

__device__ __forceinline__ unsigned short bf16_rne(float v, float* back) {
    unsigned u = __float_as_uint(v);
    unsigned r = (u + 0x7FFFu + ((u >> 16) & 1u)) >> 16;
    *back = __uint_as_float(r << 16);
    return (unsigned short)r;
}

__device__ __forceinline__ void split8(const float* p, short8& h8, short8& l8) {
    float4 u0 = *reinterpret_cast<const float4*>(p);
    float4 u1 = *reinterpret_cast<const float4*>(p + 4);
    float vv[8] = {u0.x, u0.y, u0.z, u0.w, u1.x, u1.y, u1.z, u1.w};
#pragma unroll
    for (int j = 0; j < 8; ++j) {
        float back, d;
        h8[j] = (short)bf16_rne(vv[j], &back);
        l8[j] = (short)bf16_rne(vv[j] - back, &d);
    }
}

// ---------------------------------------------------------------------------
// Pack B[K x Ncols] (row stride ldb, starting col col0) into MFMA frag order:
// [nblk][kg][col16][e8], KG = 4*ceil(K/32). Zero-pad k >= K.
// ---------------------------------------------------------------------------
__global__ void pack_b_kernel(const float* __restrict__ B, int K, int ldb, int col0,
                              int Ncols, short* __restrict__ hi, short* __restrict__ lo) {
    int KG = 4 * ((K + 31) / 32);
    int idx = blockIdx.x * blockDim.x + threadIdx.x;
    int total = (Ncols >> 4) * KG * 16;
    if (idx >= total) return;
    int col = idx & 15;
    int kg = (idx >> 4) % KG;
    int nblk = idx / (16 * KG);
    size_t o = (size_t)idx * 8;
#pragma unroll
    for (int e = 0; e < 8; ++e) {
        int k = kg * 8 + e;
        float v = (k < K) ? B[(size_t)k * ldb + col0 + nblk * 16 + col] : 0.f;
        float hf, d;
        unsigned short h = bf16_rne(v, &hf);
        unsigned short l = bf16_rne(v - hf, &d);
        hi[o + e] = (short)h;
        lo[o + e] = (short)l;
    }
}

// ---------------------------------------------------------------------------
// Generic split-bf16 GEMM: C = act(A[M,K] @ B + bias), act 0/1(lrelu)/2(relu)/3(elu)
// optional rowdot: rdout[m] += sum_c rdw[c]*v (atomic, post-act)
// optional rowmask: rows with rowmask[m]==0 output exactly 0 (empty segments)
// ---------------------------------------------------------------------------
__global__ __launch_bounds__(256) void mfma_gemm(
    const float* __restrict__ A, int K,
    const short* __restrict__ Bhi, const short* __restrict__ Blo, int KG,
    const float* __restrict__ bias, float* __restrict__ C, int M, int N, int act,
    const float* __restrict__ rdw, float* __restrict__ rdout,
    const float* __restrict__ rowmask)
{
    const int t = threadIdx.x, lane = t & 63, w = t >> 6;
    const int wm = w & 1, wn = w >> 1, q = lane >> 4, r16 = lane & 15;
    const int m0 = blockIdx.x * 64, n0 = blockIdx.y * 64;
    const int KT = K >> 5;

    f32x4 acc[2][2];
#pragma unroll
    for (int a = 0; a < 2; ++a)
#pragma unroll
        for (int b = 0; b < 2; ++b) { acc[a][b][0]=0.f; acc[a][b][1]=0.f; acc[a][b][2]=0.f; acc[a][b][3]=0.f; }

    int arow[2];
#pragma unroll
    for (int mt = 0; mt < 2; ++mt) {
        int m = m0 + (wm << 5) + (mt << 4) + r16;
        arow[mt] = (m >= M) ? M - 1 : m;
    }

    for (int kt = 0; kt < KT; ++kt) {
        short8 ah[2], al[2];
#pragma unroll
        for (int mt = 0; mt < 2; ++mt)
            split8(A + (size_t)arow[mt] * K + (kt << 5) + (q << 3), ah[mt], al[mt]);
        const int kg = (kt << 2) + q;
#pragma unroll
        for (int nt = 0; nt < 2; ++nt) {
            int nblk = (n0 >> 4) + (wn << 1) + nt;
            size_t boff = (((size_t)nblk * KG + kg) * 16 + r16) * 8;
            short8 bh = *reinterpret_cast<const short8*>(Bhi + boff);
            short8 bl = *reinterpret_cast<const short8*>(Blo + boff);
#pragma unroll
            for (int mt = 0; mt < 2; ++mt) {
                acc[mt][nt] = __builtin_amdgcn_mfma_f32_16x16x32_bf16(ah[mt], bh, acc[mt][nt], 0, 0, 0);
                acc[mt][nt] = __builtin_amdgcn_mfma_f32_16x16x32_bf16(ah[mt], bl, acc[mt][nt], 0, 0, 0);
                acc[mt][nt] = __builtin_amdgcn_mfma_f32_16x16x32_bf16(al[mt], bh, acc[mt][nt], 0, 0, 0);
            }
        }
    }

#pragma unroll
    for (int mt = 0; mt < 2; ++mt) {
        float pv[4] = {0.f, 0.f, 0.f, 0.f};
#pragma unroll
        for (int nt = 0; nt < 2; ++nt) {
            int col = n0 + (wn << 5) + (nt << 4) + r16;
            float bi = bias ? bias[col] : 0.f;
            float wc = rdw ? rdw[col] : 0.f;
#pragma unroll
            for (int i = 0; i < 4; ++i) {
                int m = m0 + (wm << 5) + (mt << 4) + (q << 2) + i;
                float v = acc[mt][nt][i] + bi;
                if (act == 1) v = v > 0.f ? v : 0.01f * v;
                else if (act == 2) v = fmaxf(v, 0.f);
                else if (act == 3) v = v > 0.f ? v : expf(v) - 1.f;
                if (rowmask && m < M && rowmask[m] == 0.f) v = 0.f;
                pv[i] += wc * v;
                if (m < M) C[(size_t)m * N + col] = v;
            }
        }
        if (rdw) {
#pragma unroll
            for (int i = 0; i < 4; ++i) {
                float p = pv[i];
                p += __shfl_xor(p, 1); p += __shfl_xor(p, 2);
                p += __shfl_xor(p, 4); p += __shfl_xor(p, 8);
                int m = m0 + (wm << 5) + (mt << 4) + (q << 2) + i;
                if (r16 == 0 && m < M) atomicAdd(&rdout[m], p);
            }
        }
    }
}

// ---------------------------------------------------------------------------
// Fused edge kernel. Block = 64 edges x 128 msg cols. 4 waves, each 32x64.
// Stage 1: e = lrelu(edge_raw @ We0 + be0) -> LDS (bf16 hi|lo packed u32,
//          row stride 132 words).
// Stage 2: msg = lrelu([h[src], e] @ We + be) in acc.
// pass 0: sc[m] += msg . wal  (atomic rowdot; sc pre-zeroed)
// pass 1: S[dst[m]] += sc[m] * msg  (att-weighted scatter; S pre-zeroed)
// ---------------------------------------------------------------------------
__global__ __launch_bounds__(256) void msg_pass_kernel(
    const float* __restrict__ h, const int* __restrict__ src, const int* __restrict__ dst,
    const float* __restrict__ edge,
    const short* __restrict__ W0hi, const short* __restrict__ W0lo,
    const float* __restrict__ be0,
    const short* __restrict__ Wehi, const short* __restrict__ Welo,
    const float* __restrict__ be,
    const float* __restrict__ wal,
    float* __restrict__ sc, float* __restrict__ S,
    int E, int pass)
{
    __shared__ unsigned int elds[64 * 132];
    const int t = threadIdx.x, lane = t & 63, w = t >> 6;
    const int wm = w & 1, wn = w >> 1, q = lane >> 4, r16 = lane & 15;
    const int e0 = blockIdx.x * 64;

    // ---- stage 1: e tile ----
    {
        f32x4 ea[2][4];
#pragma unroll
        for (int a = 0; a < 2; ++a)
#pragma unroll
            for (int b = 0; b < 4; ++b) { ea[a][b][0]=0.f; ea[a][b][1]=0.f; ea[a][b][2]=0.f; ea[a][b][3]=0.f; }
        short8 eah[2], eal[2];
#pragma unroll
        for (int mt = 0; mt < 2; ++mt) {
            int er = e0 + (wm << 5) + (mt << 4) + r16;
            if (er >= E) er = E - 1;
            if (q < 2) split8(edge + (size_t)er * 16 + (q << 3), eah[mt], eal[mt]);
            else {
#pragma unroll
                for (int j = 0; j < 8; ++j) { eah[mt][j] = 0; eal[mt][j] = 0; }
            }
        }
#pragma unroll
        for (int nt = 0; nt < 4; ++nt) {
            int nblk = (wn << 2) + nt;
            size_t boff = (((size_t)nblk * 4 + q) * 16 + r16) * 8;
            short8 bh = *reinterpret_cast<const short8*>(W0hi + boff);
            short8 bl = *reinterpret_cast<const short8*>(W0lo + boff);
#pragma unroll
            for (int mt = 0; mt < 2; ++mt) {
                ea[mt][nt] = __builtin_amdgcn_mfma_f32_16x16x32_bf16(eah[mt], bh, ea[mt][nt], 0, 0, 0);
                ea[mt][nt] = __builtin_amdgcn_mfma_f32_16x16x32_bf16(eah[mt], bl, ea[mt][nt], 0, 0, 0);
                ea[mt][nt] = __builtin_amdgcn_mfma_f32_16x16x32_bf16(eal[mt], bh, ea[mt][nt], 0, 0, 0);
            }
        }
#pragma unroll
        for (int mt = 0; mt < 2; ++mt)
#pragma unroll
            for (int nt = 0; nt < 4; ++nt) {
                int col = (wn << 6) + (nt << 4) + r16;
#pragma unroll
                for (int i = 0; i < 4; ++i) {
                    int row = (wm << 5) + (mt << 4) + (q << 2) + i;
                    float v = lrelu_f(ea[mt][nt][i] + be0[col]);
                    float back, d;
                    unsigned short hh = bf16_rne(v, &back);
                    unsigned short ll = bf16_rne(v - back, &d);
                    elds[row * 132 + col] = ((unsigned)hh << 16) | (unsigned)ll;
                }
            }
    }
    __syncthreads();

    // ---- stage 2: msg ----
    f32x4 acc[2][4];
#pragma unroll
    for (int a = 0; a < 2; ++a)
#pragma unroll
        for (int b = 0; b < 4; ++b) { acc[a][b][0]=0.f; acc[a][b][1]=0.f; acc[a][b][2]=0.f; acc[a][b][3]=0.f; }
    int grow[2];
#pragma unroll
    for (int mt = 0; mt < 2; ++mt) {
        int m = e0 + (wm << 5) + (mt << 4) + r16;
        if (m >= E) m = E - 1;
        grow[mt] = src[m];
    }
#pragma unroll
    for (int kt = 0; kt < 8; ++kt) {
        short8 ah[2], al[2];
#pragma unroll
        for (int mt = 0; mt < 2; ++mt) {
            if (kt < 4) {
                split8(h + (size_t)grow[mt] * HD + (kt << 5) + (q << 3), ah[mt], al[mt]);
            } else {
                int base = ((wm << 5) + (mt << 4) + r16) * 132 + ((kt - 4) << 5) + (q << 3);
                uint4 w0 = *reinterpret_cast<const uint4*>(&elds[base]);
                uint4 w1 = *reinterpret_cast<const uint4*>(&elds[base + 4]);
                unsigned ww[8] = {w0.x, w0.y, w0.z, w0.w, w1.x, w1.y, w1.z, w1.w};
#pragma unroll
                for (int j = 0; j < 8; ++j) {
                    ah[mt][j] = (short)(ww[j] >> 16);
                    al[mt][j] = (short)(ww[j] & 0xffffu);
                }
            }
        }
        const int kg = (kt << 2) + q;
#pragma unroll
        for (int nt = 0; nt < 4; ++nt) {
            int nblk = (wn << 2) + nt;
            size_t boff = (((size_t)nblk * 32 + kg) * 16 + r16) * 8;
            short8 bh = *reinterpret_cast<const short8*>(Wehi + boff);
            short8 bl = *reinterpret_cast<const short8*>(Welo + boff);
#pragma unroll
            for (int mt = 0; mt < 2; ++mt) {
                acc[mt][nt] = __builtin_amdgcn_mfma_f32_16x16x32_bf16(ah[mt], bh, acc[mt][nt], 0, 0, 0);
                acc[mt][nt] = __builtin_amdgcn_mfma_f32_16x16x32_bf16(ah[mt], bl, acc[mt][nt], 0, 0, 0);
                acc[mt][nt] = __builtin_amdgcn_mfma_f32_16x16x32_bf16(al[mt], bh, acc[mt][nt], 0, 0, 0);
            }
        }
    }

    if (pass == 0) {
#pragma unroll
        for (int mt = 0; mt < 2; ++mt) {
            float pv[4] = {0.f, 0.f, 0.f, 0.f};
#pragma unroll
            for (int nt = 0; nt < 4; ++nt) {
                int col = (wn << 6) + (nt << 4) + r16;
                float bi = be[col], wc = wal[col];
#pragma unroll
                for (int i = 0; i < 4; ++i)
                    pv[i] += wc * lrelu_f(acc[mt][nt][i] + bi);
            }
#pragma unroll
            for (int i = 0; i < 4; ++i) {
                float p = pv[i];
                p += __shfl_xor(p, 1); p += __shfl_xor(p, 2);
                p += __shfl_xor(p, 4); p += __shfl_xor(p, 8);
                int m = e0 + (wm << 5) + (mt << 4) + (q << 2) + i;
                if (r16 == 0 && m < E) atomicAdd(&sc[m], p);
            }
        }
    } else {
#pragma unroll
        for (int mt = 0; mt < 2; ++mt)
#pragma unroll
            for (int i = 0; i < 4; ++i) {
                int m = e0 + (wm << 5) + (mt << 4) + (q << 2) + i;
                if (m >= E) continue;
                float a = sc[m];
                int dn = dst[m];
#pragma unroll
                for (int nt = 0; nt < 4; ++nt) {
                    int col = (wn << 6) + (nt << 4) + r16;
                    float v = lrelu_f(acc[mt][nt][i] + be[col]);
                    atomicAdd(&S[(size_t)dn * HD + col], a * v);
                }
            }
    }
}

// ---------------------------------------------------------------------------
// Fused GRU: out = relu(GRU(ctx, h)). Gate-sliced packed weights:
// ghi/glo hold 6 slices (ih_r, ih_z, ih_n, hh_r, hh_z, hh_n), stride SL.
// Block 64 rows x 64 output cols, grid (ceil(M/64), 2).
// ---------------------------------------------------------------------------
#define GRU_SL (8 * 16 * 16 * 8)
__global__ __launch_bounds__(256) void gru_fused_kernel(
    const float* __restrict__ ctxb, const float* __restrict__ hb,
    const short* __restrict__ ghi, const short* __restrict__ glo,
    const float* __restrict__ bih, const float* __restrict__ bhh,
    float* __restrict__ out, int M)
{
    const int t = threadIdx.x, lane = t & 63, w = t >> 6;
    const int wm = w & 1, wn = w >> 1, q = lane >> 4, r16 = lane & 15;
    const int m0 = blockIdx.x * 64, j0 = blockIdx.y * 64;

    f32x4 acc[6][2][2];
#pragma unroll
    for (int g = 0; g < 6; ++g)
#pragma unroll
        for (int a = 0; a < 2; ++a)
#pragma unroll
            for (int b = 0; b < 2; ++b) { acc[g][a][b][0]=0.f; acc[g][a][b][1]=0.f; acc[g][a][b][2]=0.f; acc[g][a][b][3]=0.f; }

    int arow[2];
#pragma unroll
    for (int mt = 0; mt < 2; ++mt) {
        int m = m0 + (wm << 5) + (mt << 4) + r16;
        arow[mt] = (m >= M) ? M - 1 : m;
    }

    // ih gates (A = ctx)
#pragma unroll
    for (int kt = 0; kt < 4; ++kt) {
        short8 ah[2], al[2];
#pragma unroll
        for (int mt = 0; mt < 2; ++mt)
            split8(ctxb + (size_t)arow[mt] * HD + (kt << 5) + (q << 3), ah[mt], al[mt]);
        const int kg = (kt << 2) + q;
#pragma unroll
        for (int g = 0; g < 3; ++g)
#pragma unroll
            for (int nt = 0; nt < 2; ++nt) {
                int nblk = (j0 >> 4) + (wn << 1) + nt;
                size_t boff = (size_t)g * GRU_SL + (((size_t)nblk * 16 + kg) * 16 + r16) * 8;
                short8 bh = *reinterpret_cast<const short8*>(ghi + boff);
                short8 bl = *reinterpret_cast<const short8*>(glo + boff);
#pragma unroll
                for (int mt = 0; mt < 2; ++mt) {
                    acc[g][mt][nt] = __builtin_amdgcn_mfma_f32_16x16x32_bf16(ah[mt], bh, acc[g][mt][nt], 0, 0, 0);
                    acc[g][mt][nt] = __builtin_amdgcn_mfma_f32_16x16x32_bf16(ah[mt], bl, acc[g][mt][nt], 0, 0, 0);
                    acc[g][mt][nt] = __builtin_amdgcn_mfma_f32_16x16x32_bf16(al[mt], bh, acc[g][mt][nt], 0, 0, 0);
                }
            }
    }
    // hh gates (A = h)
#pragma unroll
    for (int kt = 0; kt < 4; ++kt) {
        short8 ah[2], al[2];
#pragma unroll
        for (int mt = 0; mt < 2; ++mt)
            split8(hb + (size_t)arow[mt] * HD + (kt << 5) + (q << 3), ah[mt], al[mt]);
        const int kg = (kt << 2) + q;
#pragma unroll
        for (int g = 3; g < 6; ++g)
#pragma unroll
            for (int nt = 0; nt < 2; ++nt) {
                int nblk = (j0 >> 4) + (wn << 1) + nt;
                size_t boff = (size_t)g * GRU_SL + (((size_t)nblk * 16 + kg) * 16 + r16) * 8;
                short8 bh = *reinterpret_cast<const short8*>(ghi + boff);
                short8 bl = *reinterpret_cast<const short8*>(glo + boff);
#pragma unroll
                for (int mt = 0; mt < 2; ++mt) {
                    acc[g][mt][nt] = __builtin_amdgcn_mfma_f32_16x16x32_bf16(ah[mt], bh, acc[g][mt][nt], 0, 0, 0);
                    acc[g][mt][nt] = __builtin_amdgcn_mfma_f32_16x16x32_bf16(ah[mt], bl, acc[g][mt][nt], 0, 0, 0);
                    acc[g][mt][nt] = __builtin_amdgcn_mfma_f32_16x16x32_bf16(al[mt], bh, acc[g][mt][nt], 0, 0, 0);
                }
            }
    }

#pragma unroll
    for (int mt = 0; mt < 2; ++mt)
#pragma unroll
        for (int nt = 0; nt < 2; ++nt) {
            int j = j0 + (wn << 5) + (nt << 4) + r16;
            float bir = bih[j], biz = bih[HD + j], bin = bih[2 * HD + j];
            float bhr = bhh[j], bhz = bhh[HD + j], bhn = bhh[2 * HD + j];
#pragma unroll
            for (int i = 0; i < 4; ++i) {
                int m = m0 + (wm << 5) + (mt << 4) + (q << 2) + i;
                if (m >= M) continue;
                float r = sigmoid_f(acc[0][mt][nt][i] + bir + acc[3][mt][nt][i] + bhr);
                float z = sigmoid_f(acc[1][mt][nt][i] + biz + acc[4][mt][nt][i] + bhz);
                float hn = acc[5][mt][nt][i] + bhn;
                float nn = tanhf(acc[2][mt][nt][i] + bin + r * hn);
                float hv = hb[(size_t)m * HD + j];
                out[(size_t)m * HD + j] = fmaxf((1.f - z) * nn + z * hv, 0.f);
            }
        }
}

__global__ void init_maxsum_kernel(float* mx, float* sm, int n) {
    int i = blockIdx.x * blockDim.x + threadIdx.x;
    if (i < n) { mx[i] = -__builtin_inff(); sm[i] = 0.f; }
}

__global__ void score_combine_kernel(float* __restrict__ sc, const float* __restrict__ hd2,
                                     const int* __restrict__ seg, const float* __restrict__ bal,
                                     float* __restrict__ maxbuf, int count) {
    int i = blockIdx.x * blockDim.x + threadIdx.x;
    if (i >= count) return;
    int s = seg[i];
    float v = lrelu_f(sc[i] + hd2[s] + bal[0]);
    sc[i] = v;
    atomicMaxF(&maxbuf[s], v);
}

__global__ __launch_bounds__(256) void score_kernel(
    const float* __restrict__ A, const float* __restrict__ B,
    const int* __restrict__ seg, const float* __restrict__ w,
    const float* __restrict__ bal, float* __restrict__ out,
    float* __restrict__ maxbuf, int count)
{
    int i = (blockIdx.x * blockDim.x + threadIdx.x) >> 6;
    int lane = threadIdx.x & 63;
    if (i >= count) return;
    int s = seg[i];
    const float* ar = A + (size_t)i * HD;
    const float* br = B + (size_t)s * HD;
    float p = ar[lane] * w[lane] + ar[lane + 64] * w[lane + 64]
            + br[lane] * w[128 + lane] + br[lane + 64] * w[192 + lane];
#pragma unroll
    for (int off = 32; off > 0; off >>= 1) p += __shfl_down(p, off);
    if (lane == 0) {
        float v = lrelu_f(p + bal[0]);
        out[i] = v;
        atomicMaxF(&maxbuf[s], v);
    }
}

__global__ void expsum_kernel(float* __restrict__ sc, const float* __restrict__ mx,
                              float* __restrict__ sm, const int* __restrict__ seg, int count) {
    int i = blockIdx.x * blockDim.x + threadIdx.x;
    if (i >= count) return;
    int s = seg[i];
    float p = expf(sc[i] - mx[s]);
    sc[i] = p;
    atomicAdd(&sm[s], p);
}

__global__ void attdiv_kernel(float* __restrict__ sc, const float* __restrict__ sm,
                              const int* __restrict__ seg, int count) {
    int i = blockIdx.x * blockDim.x + threadIdx.x;
    if (i >= count) return;
    sc[i] = sc[i] / sm[seg[i]];
}

__global__ void gru_gate_kernel(const float* __restrict__ gi, const float* __restrict__ gh,
                                const float* __restrict__ h, float* __restrict__ out, int M) {
    size_t idx = (size_t)blockIdx.x * blockDim.x + threadIdx.x;
    if (idx >= (size_t)M * HD) return;
    size_t row = idx >> 7; int col = (int)(idx & 127);
    const float* gir = gi + row * H3;
    const float* ghr = gh + row * H3;
    float r = sigmoid_f(gir[col] + ghr[col]);
    float z = sigmoid_f(gir[col + 128] + ghr[col + 128]);
    float nn = tanhf(gir[col + 256] + r * ghr[col + 256]);
    float o = (1.f - z) * nn + z * h[idx];
    out[idx] = fmaxf(o, 0.f);
}

__global__ void lrelu_copy_kernel(const float* __restrict__ in, float* __restrict__ out, size_t n) {
    size_t i = (size_t)blockIdx.x * blockDim.x + threadIdx.x;
    if (i >= n) return;
    out[i] = lrelu_f(in[i]);
}

__global__ void segsum_kernel(const float* __restrict__ nb, const int* __restrict__ gid,
                              float* __restrict__ sn, int Nn) {
    size_t idx = (size_t)blockIdx.x * blockDim.x + threadIdx.x;
    if (idx >= (size_t)Nn * HD) return;
    size_t row = idx >> 7; int col = (int)(idx & 127);
    atomicAdd(&sn[(size_t)gid[row] * HD + col], nb[idx]);
}

__global__ void seg_scale_sum_kernel(const float* __restrict__ nb, const int* __restrict__ gid,
                                     const float* __restrict__ scale, float* __restrict__ out, int Nn) {
    size_t idx = (size_t)blockIdx.x * blockDim.x + threadIdx.x;
    if (idx >= (size_t)Nn * HD) return;
    size_t row = idx >> 7; int col = (int)(idx & 127);
    atomicAdd(&out[(size_t)gid[row] * HD + col], scale[row] * nb[idx]);
}

__global__ void final_kernel(const float* __restrict__ sn, const float* __restrict__ Wp,
                             const float* __restrict__ bp, float* __restrict__ out, int G) {
    int g = (blockIdx.x * blockDim.x + threadIdx.x) >> 6;
    int lane = threadIdx.x & 63;
    if (g >= G) return;
    const float* r = sn + (size_t)g * HD;
    float p = r[lane] * Wp[lane] + r[lane + 64] * Wp[lane + 64];
#pragma unroll
    for (int off = 32; off > 0; off >>= 1) p += __shfl_down(p, off);
    if (lane == 0) out[g] = p + bp[0];
}

__global__ void canary_kernel(float* out, int n) {
    int i = blockIdx.x * blockDim.x + threadIdx.x;
    if (i < n) out[i] = 123.456f;
}

struct PkB { const short* hi; const short* lo; int KG; };

extern "C" void kernel_launch(void* const* d_in, const int* in_sizes, int n_in,
                              void* d_out, int out_size, void* d_ws, size_t ws_size,
                              hipStream_t stream) {
    const float* node = (const float*)d_in[0];
    const float* edge = (const float*)d_in[1];
    const int*   src  = (const int*)d_in[2];
    const int*   dst  = (const int*)d_in[3];
    const int*   gid  = (const int*)d_in[4];
    const float* Wn0  = (const float*)d_in[5];
    const float* bn0  = (const float*)d_in[6];
    const float* We0  = (const float*)d_in[7];
    const float* be0  = (const float*)d_in[8];
    const float* aWn  = (const float*)d_in[9];
    const float* abn  = (const float*)d_in[10];
    const float* aWe  = (const float*)d_in[11];
    const float* abe  = (const float*)d_in[12];
    const float* aWal = (const float*)d_in[13];
    const float* abal = (const float*)d_in[14];
    const float* aWat = (const float*)d_in[15];
    const float* abat = (const float*)d_in[16];
    const float* aWih = (const float*)d_in[17];
    const float* abih = (const float*)d_in[18];
    const float* aWhh = (const float*)d_in[19];
    const float* abhh = (const float*)d_in[20];
    const float* mWal = (const float*)d_in[21];
    const float* mbal = (const float*)d_in[22];
    const float* mWat = (const float*)d_in[23];
    const float* mbat = (const float*)d_in[24];
    const float* mWih = (const float*)d_in[25];
    const float* mbih = (const float*)d_in[26];
    const float* mWhh = (const float*)d_in[27];
    const float* mbhh = (const float*)d_in[28];
    const float* Wp   = (const float*)d_in[29];
    const float* bp   = (const float*)d_in[30];

    const int N = in_sizes[0] / 64;
    const int E = in_sizes[1] / 16;
    const int G = out_size;
    const int D = in_sizes[9] / (HD * HD);
    const int L = in_sizes[21] / (2 * HD);
    if (D > 8 || L > 4) return;

    char* wsb = (char*)d_ws;

    // ---- weight pre-pack region ----
    short* pkcur = (short*)wsb;
    auto packB = [&](const float* B, int K, int ldb, int col0, int Ncols) -> PkB {
        int KG = 4 * ((K + 31) / 32);
        size_t elems = (size_t)(Ncols >> 4) * KG * 16 * 8;
        short* hi = pkcur; pkcur += elems;
        short* lo = pkcur; pkcur += elems;
        int total = (Ncols >> 4) * KG * 16;
        pack_b_kernel<<<(total + 255) / 256, 256, 0, stream>>>(B, K, ldb, col0, Ncols, hi, lo);
        PkB p; p.hi = hi; p.lo = lo; p.KG = KG; return p;
    };
    PkB pWn0 = packB(Wn0, 64, HD, 0, HD);
    PkB pWe0 = packB(We0, 16, HD, 0, HD);
    PkB pAWn[8], pAWe[8], pAWat[8];
    const short *gHi[8], *gLo[8];
    for (int d = 0; d < D; ++d) {
        pAWn[d]  = packB(aWn  + (size_t)d * HD * HD,     HD,     HD, 0, HD);
        pAWe[d]  = packB(aWe  + (size_t)d * 2 * HD * HD, 2 * HD, HD, 0, HD);
        pAWat[d] = packB(aWat + (size_t)d * HD * HD,     HD,     HD, 0, HD);
        short* ghi = pkcur; pkcur += 6 * GRU_SL;
        short* glo = pkcur; pkcur += 6 * GRU_SL;
        for (int g = 0; g < 3; ++g) {
            int total = (HD >> 4) * 16 * 16;
            pack_b_kernel<<<(total + 255) / 256, 256, 0, stream>>>(
                aWih + (size_t)d * HD * H3, HD, H3, g * HD, HD, ghi + g * GRU_SL, glo + g * GRU_SL);
            pack_b_kernel<<<(total + 255) / 256, 256, 0, stream>>>(
                aWhh + (size_t)d * HD * H3, HD, H3, g * HD, HD, ghi + (3 + g) * GRU_SL, glo + (3 + g) * GRU_SL);
        }
        gHi[d] = ghi; gLo[d] = glo;
    }
    PkB pMWat[4], pMWih[4], pMWhh[4];
    for (int l = 0; l < L; ++l) {
        pMWat[l] = packB(mWat + (size_t)l * HD * HD, HD, HD, 0, HD);
        pMWih[l] = packB(mWih + (size_t)l * HD * H3, HD, H3, 0, H3);
        pMWhh[l] = packB(mWhh + (size_t)l * HD * H3, HD, H3, 0, H3);
    }

    // ---- f32 workspace ----
    size_t off = ((size_t)((char*)pkcur - wsb) + 255) & ~(size_t)255;
    auto alloc = [&](size_t bytes) -> float* {
        float* p = (float*)(wsb + off);
        off += (bytes + 255) & ~(size_t)255;
        return p;
    };
    float* nbuf = alloc((size_t)N * HD * 4);   // node state n; aliased as S in pass B
    float* hbuf = alloc((size_t)N * HD * 4);
    float* ctx  = alloc((size_t)N * HD * 4);
    float* sc_e = alloc((size_t)E * 4);
    float* nmax = alloc((size_t)N * 4);
    float* nsum = alloc((size_t)N * 4);
    float* sc_n = alloc((size_t)N * 4);
    float* hd2  = alloc((size_t)N * 4);
    float* sn   = alloc((size_t)G * HD * 4);
    float* sbuf = alloc((size_t)G * HD * 4);
    float* sctx = alloc((size_t)G * HD * 4);
    float* Sg   = alloc((size_t)G * HD * 4);
    float* gim  = alloc((size_t)G * H3 * 4);
    float* ghm  = alloc((size_t)G * H3 * 4);
    float* gmax = alloc((size_t)G * 4);
    float* gsum = alloc((size_t)G * 4);
    if (off > ws_size) {
        canary_kernel<<<(G + 255) / 256, 256, 0, stream>>>((float*)d_out, G);
        return;
    }

    auto mgemm = [&](const float* A, int K, const PkB& pk, const float* bias, float* C,
                     int M, int Nc, int act, const float* rdw, float* rdout,
                     const float* rowmask) {
        dim3 g((M + 63) / 64, Nc / 64);
        mfma_gemm<<<g, dim3(256), 0, stream>>>(A, K, pk.hi, pk.lo, pk.KG, bias, C, M, Nc,
                                               act, rdw, rdout, rowmask);
    };

    // ---- input embedding ----
    mgemm(node, 64, pWn0, bn0, nbuf, N, HD, 1, nullptr, nullptr, nullptr);

    // ---- atom-level message passing ----
    const int EB = (E + 63) / 64;
    for (int d = 0; d < D; ++d) {
        const float* bn_d  = abn  + (size_t)d * HD;
        const float* be_d  = abe  + (size_t)d * HD;
        const float* Wal_d = aWal + (size_t)d * 2 * HD;
        const float* bal_d = abal + d;
        const float* bat_d = abat + (size_t)d * HD;
        const float* bih_d = abih + (size_t)d * H3;
        const float* bhh_d = abhh + (size_t)d * H3;

        hipMemsetAsync(hd2, 0, (size_t)N * 4, stream);
        hipMemsetAsync(sc_e, 0, (size_t)E * 4, stream);
        // h = lrelu(n @ Wn + bn); rowdot hd2 = h . Wal[128:256]
        mgemm(nbuf, HD, pAWn[d], bn_d, hbuf, N, HD, 1, Wal_d + HD, hd2, nullptr);
        init_maxsum_kernel<<<(N + 255) / 256, 256, 0, stream>>>(nmax, nsum, N);
        // pass A: sc_e = msg . Wal[0:128]
        msg_pass_kernel<<<EB, 256, 0, stream>>>(hbuf, src, dst, edge, pWe0.hi, pWe0.lo, be0,
                                                pAWe[d].hi, pAWe[d].lo, be_d, Wal_d,
                                                sc_e, nullptr, E, 0);
        score_combine_kernel<<<(E + 255) / 256, 256, 0, stream>>>(sc_e, hd2, dst, bal_d, nmax, E);
        expsum_kernel<<<(E + 255) / 256, 256, 0, stream>>>(sc_e, nmax, nsum, dst, E);
        attdiv_kernel<<<(E + 255) / 256, 256, 0, stream>>>(sc_e, nsum, dst, E);
        // pass B: S (= nbuf) = segsum(att * msg)
        hipMemsetAsync(nbuf, 0, (size_t)N * HD * 4, stream);
        msg_pass_kernel<<<EB, 256, 0, stream>>>(hbuf, src, dst, edge, pWe0.hi, pWe0.lo, be0,
                                                pAWe[d].hi, pAWe[d].lo, be_d, nullptr,
                                                sc_e, nbuf, E, 1);
        // ctx = elu(S @ Wat + bat)  (sum att = 1); rows with no incoming
        // edges (nsum==0) forced to exactly 0 = elu(segment_sum(empty))
        mgemm(nbuf, HD, pAWat[d], bat_d, ctx, N, HD, 3, nullptr, nullptr, nsum);
        // n = relu(GRU(ctx, h))  -> nbuf
        dim3 gg((N + 63) / 64, 2);
        gru_fused_kernel<<<gg, dim3(256), 0, stream>>>(ctx, hbuf, gHi[d], gLo[d],
                                                       bih_d, bhh_d, nbuf, N);
    }

    // ---- molecule-level readout ----
    hipMemsetAsync(sn, 0, (size_t)G * HD * 4, stream);
    segsum_kernel<<<((size_t)N * HD + 255) / 256, 256, 0, stream>>>(nbuf, gid, sn, N);
    for (int l = 0; l < L; ++l) {
        const float* Wal_l = mWal + (size_t)l * 2 * HD;
        const float* bal_l = mbal + l;
        const float* bat_l = mbat + (size_t)l * HD;
        const float* bih_l = mbih + (size_t)l * H3;
        const float* bhh_l = mbhh + (size_t)l * H3;

        lrelu_copy_kernel<<<((size_t)G * HD + 255) / 256, 256, 0, stream>>>(sn, sbuf, (size_t)G * HD);
        init_maxsum_kernel<<<(G + 255) / 256, 256, 0, stream>>>(gmax, gsum, G);
        score_kernel<<<(N + 3) / 4, 256, 0, stream>>>(nbuf, sbuf, gid, Wal_l, bal_l, sc_n, gmax, N);
        expsum_kernel<<<(N + 255) / 256, 256, 0, stream>>>(sc_n, gmax, gsum, gid, N);
        attdiv_kernel<<<(N + 255) / 256, 256, 0, stream>>>(sc_n, gsum, gid, N);
        // Sg = segsum(aw * n); sctx = elu(Sg @ mWat + mbat)   (sum aw = 1)
        hipMemsetAsync(Sg, 0, (size_t)G * HD * 4, stream);
        seg_scale_sum_kernel<<<((size_t)N * HD + 255) / 256, 256, 0, stream>>>(nbuf, gid, sc_n, Sg, N);
        mgemm(Sg, HD, pMWat[l], bat_l, sctx, G, HD, 3, nullptr, nullptr, gsum);
        mgemm(sctx, HD, pMWih[l], bih_l, gim, G, H3, 0, nullptr, nullptr, nullptr);
        mgemm(sbuf, HD, pMWhh[l], bhh_l, ghm, G, H3, 0, nullptr, nullptr, nullptr);
        gru_gate_kernel<<<((size_t)G * HD + 255) / 256, 256, 0, stream>>>(gim, ghm, sbuf, sn, G);
    }

    // ---- final prediction ----
    final_kernel<<<(G + 3) / 4, 256, 0, stream>>>(sn, Wp, bp, (float*)d_out, G);
}